// Round 1
// baseline (1153.123 us; speedup 1.0000x reference)
//
#include <hip/hip_runtime.h>
#include <hip/hip_bf16.h>
#include <math.h>

// Problem constants (H=1024, E=8, I=4096, T=B*S=4096)
#define H_DIM 1024
#define E_NUM 8
#define I_DIM 4096
#define T_NUM 4096
#define CAP   8192   // 2*T worst-case pairs per expert

typedef __attribute__((ext_vector_type(8))) short bf16x8;
typedef __attribute__((ext_vector_type(4))) float f32x4;

__device__ inline unsigned short f2bf(float f) {
  union { __hip_bfloat16 h; unsigned short u; } cv;
  cv.h = __float2bfloat16(f);   // RNE
  return cv.u;
}

// ---------------- Router: 1 wave per token ----------------
__global__ void router_kernel(const float* __restrict__ x,
                              const float* __restrict__ gw,
                              const float* __restrict__ gb,
                              int* __restrict__ cnt,
                              int* __restrict__ list,
                              float* __restrict__ tokw) {
  const int t = blockIdx.x;
  const int l = threadIdx.x;
  const float* xr = x + (size_t)t * H_DIM;
  float acc[E_NUM];
#pragma unroll
  for (int e = 0; e < E_NUM; ++e) acc[e] = 0.f;
#pragma unroll
  for (int j = 0; j < H_DIM / 64; ++j) {
    const int h = l + j * 64;
    const float xv = xr[h];
    const float4* g = (const float4*)(gw + (size_t)h * E_NUM);
    const float4 g0 = g[0], g1 = g[1];
    acc[0] += xv * g0.x; acc[1] += xv * g0.y; acc[2] += xv * g0.z; acc[3] += xv * g0.w;
    acc[4] += xv * g1.x; acc[5] += xv * g1.y; acc[6] += xv * g1.z; acc[7] += xv * g1.w;
  }
#pragma unroll
  for (int off = 32; off > 0; off >>= 1) {
#pragma unroll
    for (int e = 0; e < E_NUM; ++e) acc[e] += __shfl_down(acc[e], off, 64);
  }
  if (l == 0) {
    float lg[E_NUM], mx = -1e30f;
#pragma unroll
    for (int e = 0; e < E_NUM; ++e) { lg[e] = acc[e] + gb[e]; mx = fmaxf(mx, lg[e]); }
    float p[E_NUM], s = 0.f;
#pragma unroll
    for (int e = 0; e < E_NUM; ++e) { p[e] = expf(lg[e] - mx); s += p[e]; }
    const float inv = 1.f / s;
#pragma unroll
    for (int e = 0; e < E_NUM; ++e) p[e] *= inv;
    // top-2, ties -> lowest index (matches jax.lax.top_k)
    int i0 = 0;
#pragma unroll
    for (int e = 1; e < E_NUM; ++e) if (p[e] > p[i0]) i0 = e;
    int i1 = (i0 == 0) ? 1 : 0;
#pragma unroll
    for (int e = 0; e < E_NUM; ++e) if (e != i0 && p[e] > p[i1]) i1 = e;
    const float denom = p[i0] + p[i1] + 1e-6f;
    const float w0 = p[i0] / denom, w1 = p[i1] / denom;
    int pos = atomicAdd(&cnt[i0], 1);
    list[i0 * CAP + pos] = t * 2;
    tokw[t * 2] = w0;
    pos = atomicAdd(&cnt[i1], 1);
    list[i1 * CAP + pos] = t * 2 + 1;
    tokw[t * 2 + 1] = w1;
  }
}

// ---------------- Scan: exclusive prefix of counts ----------------
__global__ void scan_kernel(const int* __restrict__ cnt, int* __restrict__ base) {
  if (threadIdx.x == 0 && blockIdx.x == 0) {
    int b = 0;
    for (int e = 0; e < E_NUM; ++e) { base[e] = b; b += cnt[e]; }
  }
}

// ---------------- Stage 1: hmid = gelu(x_gather @ W1[e] + b1[e]) ----------------
// Tile 128x128, BK=32, 4 waves of 64x64 each (4x4 frags of 16x16x32 MFMA).
__launch_bounds__(256)
__global__ void gemm1_kernel(const float* __restrict__ x,
                             const float* __restrict__ W1,
                             const float* __restrict__ b1,
                             const int* __restrict__ cnt,
                             const int* __restrict__ base,
                             const int* __restrict__ list,
                             unsigned short* __restrict__ hmid) {
  const int e = blockIdx.z;
  const int c = cnt[e];
  const int m0 = blockIdx.y * 128;
  if (m0 >= c) return;
  const int n0 = blockIdx.x * 128;

  __shared__ int toks[128];
  __shared__ __align__(16) unsigned short As[128 * 40];  // [row][k], ld=40 (pad)
  __shared__ __align__(16) unsigned short Bs[128 * 40];  // [n][k] transposed, ld=40

  const int tid = threadIdx.x;
  if (tid < 128) {
    int idx = m0 + tid; if (idx >= c) idx = c - 1;
    toks[tid] = list[e * CAP + idx] >> 1;
  }
  __syncthreads();

  const int lane = tid & 63;
  const int wave = tid >> 6;
  const int wm = (wave >> 1) * 64;
  const int wn = (wave & 1) * 64;
  const int l16 = lane & 15;
  const int quad = lane >> 4;

  f32x4 acc[16];
#pragma unroll
  for (int i = 0; i < 16; ++i) acc[i] = (f32x4){0.f, 0.f, 0.f, 0.f};

  const float* W1e = W1 + (size_t)e * H_DIM * I_DIM;

  for (int kt = 0; kt < H_DIM / 32; ++kt) {
    const int k0 = kt * 32;
    // A: 128 rows x 32 k fp32 (gathered) -> bf16 LDS
#pragma unroll
    for (int i = 0; i < 4; ++i) {
      const int idx = tid + i * 256;
      const int row = idx >> 3, kg = idx & 7;
      const float4 v = *(const float4*)(x + (size_t)toks[row] * H_DIM + k0 + kg * 4);
      ushort4 b;
      b.x = f2bf(v.x); b.y = f2bf(v.y); b.z = f2bf(v.z); b.w = f2bf(v.w);
      *(ushort4*)&As[row * 40 + kg * 4] = b;
    }
    // B: 32 k x 128 n fp32 -> bf16 LDS transposed [n][k]
#pragma unroll
    for (int i = 0; i < 4; ++i) {
      const int idx = tid + i * 256;
      const int kk = idx >> 5, ng = (idx & 31) * 4;
      const float4 v = *(const float4*)(W1e + (size_t)(k0 + kk) * I_DIM + n0 + ng);
      Bs[(ng + 0) * 40 + kk] = f2bf(v.x);
      Bs[(ng + 1) * 40 + kk] = f2bf(v.y);
      Bs[(ng + 2) * 40 + kk] = f2bf(v.z);
      Bs[(ng + 3) * 40 + kk] = f2bf(v.w);
    }
    __syncthreads();
    bf16x8 a[4], b[4];
#pragma unroll
    for (int mf = 0; mf < 4; ++mf)
      a[mf] = *(const bf16x8*)&As[(wm + mf * 16 + l16) * 40 + quad * 8];
#pragma unroll
    for (int nf = 0; nf < 4; ++nf)
      b[nf] = *(const bf16x8*)&Bs[(wn + nf * 16 + l16) * 40 + quad * 8];
#pragma unroll
    for (int mf = 0; mf < 4; ++mf)
#pragma unroll
      for (int nf = 0; nf < 4; ++nf)
        acc[mf * 4 + nf] = __builtin_amdgcn_mfma_f32_16x16x32_bf16(
            a[mf], b[nf], acc[mf * 4 + nf], 0, 0, 0);
    __syncthreads();
  }

  const int hb = base[e];
#pragma unroll
  for (int mf = 0; mf < 4; ++mf) {
#pragma unroll
    for (int reg = 0; reg < 4; ++reg) {
      const int row = wm + mf * 16 + quad * 4 + reg;
      const int gr = m0 + row;
      if (gr < c) {
#pragma unroll
        for (int nf = 0; nf < 4; ++nf) {
          const int col = n0 + wn + nf * 16 + l16;
          const float v = acc[mf * 4 + nf][reg] + b1[e * I_DIM + col];
          const float u = v + 0.044715f * v * v * v;
          const float g = 0.5f * v * (1.0f + tanhf(0.7978845608028654f * u));
          hmid[(size_t)(hb + gr) * I_DIM + col] = f2bf(g);
        }
      }
    }
  }
}

// ---------------- Stage 2: out[t] += w * (hmid @ W2[e] + b2[e]) ----------------
__launch_bounds__(256)
__global__ void gemm2_kernel(const unsigned short* __restrict__ hmid,
                             const float* __restrict__ W2,
                             const float* __restrict__ b2,
                             const int* __restrict__ cnt,
                             const int* __restrict__ base,
                             const int* __restrict__ list,
                             const float* __restrict__ tokw,
                             float* __restrict__ out) {
  const int e = blockIdx.z;
  const int c = cnt[e];
  const int m0 = blockIdx.y * 128;
  if (m0 >= c) return;
  const int n0 = blockIdx.x * 128;

  __shared__ int ents[128];
  __shared__ int arow[128];
  __shared__ __align__(16) unsigned short As[128 * 40];
  __shared__ __align__(16) unsigned short Bs[128 * 40];

  const int tid = threadIdx.x;
  const int hb = base[e];
  if (tid < 128) {
    int idx = m0 + tid; if (idx >= c) idx = c - 1;
    ents[tid] = list[e * CAP + idx];
    arow[tid] = hb + idx;
  }
  __syncthreads();

  const int lane = tid & 63;
  const int wave = tid >> 6;
  const int wm = (wave >> 1) * 64;
  const int wn = (wave & 1) * 64;
  const int l16 = lane & 15;
  const int quad = lane >> 4;

  f32x4 acc[16];
#pragma unroll
  for (int i = 0; i < 16; ++i) acc[i] = (f32x4){0.f, 0.f, 0.f, 0.f};

  const float* W2e = W2 + (size_t)e * I_DIM * H_DIM;

  for (int kt = 0; kt < I_DIM / 32; ++kt) {
    const int k0 = kt * 32;
    // A: 128 rows x 32 k bf16 (already bf16) -> LDS, 16B chunks
#pragma unroll
    for (int i = 0; i < 2; ++i) {
      const int idx = tid + i * 256;
      const int row = idx >> 2, kg = idx & 3;
      const f32x4 v = *(const f32x4*)(hmid + (size_t)arow[row] * I_DIM + k0 + kg * 8);
      *(f32x4*)&As[row * 40 + kg * 8] = v;
    }
    // B: 32 k x 128 n fp32 -> bf16 LDS transposed
#pragma unroll
    for (int i = 0; i < 4; ++i) {
      const int idx = tid + i * 256;
      const int kk = idx >> 5, ng = (idx & 31) * 4;
      const float4 v = *(const float4*)(W2e + (size_t)(k0 + kk) * H_DIM + n0 + ng);
      Bs[(ng + 0) * 40 + kk] = f2bf(v.x);
      Bs[(ng + 1) * 40 + kk] = f2bf(v.y);
      Bs[(ng + 2) * 40 + kk] = f2bf(v.z);
      Bs[(ng + 3) * 40 + kk] = f2bf(v.w);
    }
    __syncthreads();
    bf16x8 a[4], b[4];
#pragma unroll
    for (int mf = 0; mf < 4; ++mf)
      a[mf] = *(const bf16x8*)&As[(wm + mf * 16 + l16) * 40 + quad * 8];
#pragma unroll
    for (int nf = 0; nf < 4; ++nf)
      b[nf] = *(const bf16x8*)&Bs[(wn + nf * 16 + l16) * 40 + quad * 8];
#pragma unroll
    for (int mf = 0; mf < 4; ++mf)
#pragma unroll
      for (int nf = 0; nf < 4; ++nf)
        acc[mf * 4 + nf] = __builtin_amdgcn_mfma_f32_16x16x32_bf16(
            a[mf], b[nf], acc[mf * 4 + nf], 0, 0, 0);
    __syncthreads();
  }

#pragma unroll
  for (int mf = 0; mf < 4; ++mf) {
#pragma unroll
    for (int reg = 0; reg < 4; ++reg) {
      const int row = wm + mf * 16 + quad * 4 + reg;
      const int gr = m0 + row;
      if (gr < c) {
        const int ent = ents[row];
        const int t = ent >> 1;
        const float wgt = tokw[ent];
#pragma unroll
        for (int nf = 0; nf < 4; ++nf) {
          const int col = n0 + wn + nf * 16 + l16;
          const float v = acc[mf * 4 + nf][reg] + b2[e * H_DIM + col];
          atomicAdd(&out[(size_t)t * H_DIM + col], wgt * v);
        }
      }
    }
  }
}

extern "C" void kernel_launch(void* const* d_in, const int* in_sizes, int n_in,
                              void* d_out, int out_size, void* d_ws, size_t ws_size,
                              hipStream_t stream) {
  (void)in_sizes; (void)n_in; (void)ws_size;
  const float* x  = (const float*)d_in[0];
  const float* gw = (const float*)d_in[1];
  const float* gb = (const float*)d_in[2];
  const float* W1 = (const float*)d_in[3];
  const float* b1 = (const float*)d_in[4];
  const float* W2 = (const float*)d_in[5];
  const float* b2 = (const float*)d_in[6];
  float* out = (float*)d_out;

  char* w = (char*)d_ws;
  int* cnt   = (int*)w;                                   // 32 B
  int* base  = (int*)(w + 32);                            // 32 B
  int* list  = (int*)(w + 256);                           // 8*8192*4 = 256 KB
  float* tokw = (float*)(w + 256 + CAP * E_NUM * 4);      // 32 KB
  unsigned short* hmid = (unsigned short*)(w + 295168);   // 8192*4096*2 = 64 MB

  hipMemsetAsync(cnt, 0, 32, stream);
  hipMemsetAsync(out, 0, (size_t)out_size * sizeof(float), stream);

  router_kernel<<<T_NUM, 64, 0, stream>>>(x, gw, gb, cnt, list, tokw);
  scan_kernel<<<1, 64, 0, stream>>>(cnt, base);
  gemm1_kernel<<<dim3(I_DIM / 128, CAP / 128, E_NUM), 256, 0, stream>>>(
      x, W1, b1, cnt, base, list, hmid);
  gemm2_kernel<<<dim3(H_DIM / 128, CAP / 128, E_NUM), 256, 0, stream>>>(
      hmid, W2, b2, cnt, base, list, tokw, out);
}

// Round 2
// 750.933 us; speedup vs baseline: 1.5356x; 1.5356x over previous
//
#include <hip/hip_runtime.h>
#include <hip/hip_bf16.h>
#include <math.h>

// Problem constants (H=1024, E=8, I=4096, T=B*S=4096)
#define H_DIM 1024
#define E_NUM 8
#define I_DIM 4096
#define T_NUM 4096
#define CAP   8192   // 2*T worst-case pairs per expert

typedef __attribute__((ext_vector_type(8))) short bf16x8;
typedef __attribute__((ext_vector_type(4))) float f32x4;

__device__ inline unsigned short f2bf(float f) {
  union { __hip_bfloat16 h; unsigned short u; } cv;
  cv.h = __float2bfloat16(f);   // RNE
  return cv.u;
}

// ---------------- Router: 1 wave per token ----------------
__global__ void router_kernel(const float* __restrict__ x,
                              const float* __restrict__ gw,
                              const float* __restrict__ gb,
                              int* __restrict__ cnt,
                              int* __restrict__ list,
                              float* __restrict__ tokw) {
  const int t = blockIdx.x;
  const int l = threadIdx.x;
  const float* xr = x + (size_t)t * H_DIM;
  float acc[E_NUM];
#pragma unroll
  for (int e = 0; e < E_NUM; ++e) acc[e] = 0.f;
#pragma unroll
  for (int j = 0; j < H_DIM / 64; ++j) {
    const int h = l + j * 64;
    const float xv = xr[h];
    const float4* g = (const float4*)(gw + (size_t)h * E_NUM);
    const float4 g0 = g[0], g1 = g[1];
    acc[0] += xv * g0.x; acc[1] += xv * g0.y; acc[2] += xv * g0.z; acc[3] += xv * g0.w;
    acc[4] += xv * g1.x; acc[5] += xv * g1.y; acc[6] += xv * g1.z; acc[7] += xv * g1.w;
  }
#pragma unroll
  for (int off = 32; off > 0; off >>= 1) {
#pragma unroll
    for (int e = 0; e < E_NUM; ++e) acc[e] += __shfl_down(acc[e], off, 64);
  }
  if (l == 0) {
    float lg[E_NUM], mx = -1e30f;
#pragma unroll
    for (int e = 0; e < E_NUM; ++e) { lg[e] = acc[e] + gb[e]; mx = fmaxf(mx, lg[e]); }
    float p[E_NUM], s = 0.f;
#pragma unroll
    for (int e = 0; e < E_NUM; ++e) { p[e] = expf(lg[e] - mx); s += p[e]; }
    const float inv = 1.f / s;
#pragma unroll
    for (int e = 0; e < E_NUM; ++e) p[e] *= inv;
    // top-2, ties -> lowest index (matches jax.lax.top_k)
    int i0 = 0;
#pragma unroll
    for (int e = 1; e < E_NUM; ++e) if (p[e] > p[i0]) i0 = e;
    int i1 = (i0 == 0) ? 1 : 0;
#pragma unroll
    for (int e = 0; e < E_NUM; ++e) if (e != i0 && p[e] > p[i1]) i1 = e;
    const float denom = p[i0] + p[i1] + 1e-6f;
    const float w0 = p[i0] / denom, w1 = p[i1] / denom;
    int pos = atomicAdd(&cnt[i0], 1);
    list[i0 * CAP + pos] = t * 2;
    tokw[t * 2] = w0;
    pos = atomicAdd(&cnt[i1], 1);
    list[i1 * CAP + pos] = t * 2 + 1;
    tokw[t * 2 + 1] = w1;
  }
}

// ---------------- Scan: exclusive prefix of counts ----------------
__global__ void scan_kernel(const int* __restrict__ cnt, int* __restrict__ base) {
  if (threadIdx.x == 0 && blockIdx.x == 0) {
    int b = 0;
    for (int e = 0; e < E_NUM; ++e) { base[e] = b; b += cnt[e]; }
  }
}

// ---------------- Stage 1: hmid = gelu(x_gather @ W1[e] + b1[e]) ----------------
// Tile 128x128, BK=32, 4 waves of 64x64 each (4x4 frags of 16x16x32 MFMA).
__launch_bounds__(256)
__global__ void gemm1_kernel(const float* __restrict__ x,
                             const float* __restrict__ W1,
                             const float* __restrict__ b1,
                             const int* __restrict__ cnt,
                             const int* __restrict__ base,
                             const int* __restrict__ list,
                             unsigned short* __restrict__ hmid) {
  const int e = blockIdx.z;
  const int c = cnt[e];
  const int m0 = blockIdx.y * 128;
  if (m0 >= c) return;
  const int n0 = blockIdx.x * 128;

  __shared__ int toks[128];
  __shared__ __align__(16) unsigned short As[128 * 40];  // [row][k], ld=40 (pad)
  __shared__ __align__(16) unsigned short Bs[128 * 40];  // [n][k] transposed, ld=40

  const int tid = threadIdx.x;
  if (tid < 128) {
    int idx = m0 + tid; if (idx >= c) idx = c - 1;
    toks[tid] = list[e * CAP + idx] >> 1;
  }
  __syncthreads();

  const int lane = tid & 63;
  const int wave = tid >> 6;
  const int wm = (wave >> 1) * 64;
  const int wn = (wave & 1) * 64;
  const int l16 = lane & 15;
  const int quad = lane >> 4;

  f32x4 acc[16];
#pragma unroll
  for (int i = 0; i < 16; ++i) acc[i] = (f32x4){0.f, 0.f, 0.f, 0.f};

  const float* W1e = W1 + (size_t)e * H_DIM * I_DIM;

  for (int kt = 0; kt < H_DIM / 32; ++kt) {
    const int k0 = kt * 32;
    // A: 128 rows x 32 k fp32 (gathered) -> bf16 LDS, b128 writes.
    // item: row = idx>>2 (0..127), g = idx&3 (kgroup of 8)
#pragma unroll
    for (int i = 0; i < 2; ++i) {
      const int idx = tid + i * 256;
      const int row = idx >> 2, g = idx & 3;
      const float* src = x + (size_t)toks[row] * H_DIM + k0 + g * 8;
      const float4 v0 = *(const float4*)(src);
      const float4 v1 = *(const float4*)(src + 4);
      unsigned short tmp[8];
      tmp[0] = f2bf(v0.x); tmp[1] = f2bf(v0.y); tmp[2] = f2bf(v0.z); tmp[3] = f2bf(v0.w);
      tmp[4] = f2bf(v1.x); tmp[5] = f2bf(v1.y); tmp[6] = f2bf(v1.z); tmp[7] = f2bf(v1.w);
      *(f32x4*)&As[row * 40 + g * 8] = *(const f32x4*)tmp;
    }
    // B: [n][k] transposed stage. item: n = idx&127, g = idx>>7 (kgroup of 8).
    // 8 stride-I dword loads (lane-consecutive n => coalesced), 1 ds_write_b128.
#pragma unroll
    for (int i = 0; i < 2; ++i) {
      const int idx = tid + i * 256;
      const int n = idx & 127, g = idx >> 7;
      const float* src = W1e + (size_t)(k0 + g * 8) * I_DIM + n0 + n;
      unsigned short tmp[8];
#pragma unroll
      for (int kk = 0; kk < 8; ++kk)
        tmp[kk] = f2bf(src[(size_t)kk * I_DIM]);
      *(f32x4*)&Bs[n * 40 + g * 8] = *(const f32x4*)tmp;
    }
    __syncthreads();
    bf16x8 a[4], b[4];
#pragma unroll
    for (int mf = 0; mf < 4; ++mf)
      a[mf] = *(const bf16x8*)&As[(wm + mf * 16 + l16) * 40 + quad * 8];
#pragma unroll
    for (int nf = 0; nf < 4; ++nf)
      b[nf] = *(const bf16x8*)&Bs[(wn + nf * 16 + l16) * 40 + quad * 8];
#pragma unroll
    for (int mf = 0; mf < 4; ++mf)
#pragma unroll
      for (int nf = 0; nf < 4; ++nf)
        acc[mf * 4 + nf] = __builtin_amdgcn_mfma_f32_16x16x32_bf16(
            a[mf], b[nf], acc[mf * 4 + nf], 0, 0, 0);
    __syncthreads();
  }

  const int hb = base[e];
#pragma unroll
  for (int mf = 0; mf < 4; ++mf) {
#pragma unroll
    for (int reg = 0; reg < 4; ++reg) {
      const int row = wm + mf * 16 + quad * 4 + reg;
      const int gr = m0 + row;
      if (gr < c) {
#pragma unroll
        for (int nf = 0; nf < 4; ++nf) {
          const int col = n0 + wn + nf * 16 + l16;
          const float v = acc[mf * 4 + nf][reg] + b1[e * I_DIM + col];
          const float u = v + 0.044715f * v * v * v;
          const float g = 0.5f * v * (1.0f + tanhf(0.7978845608028654f * u));
          hmid[(size_t)(hb + gr) * I_DIM + col] = f2bf(g);
        }
      }
    }
  }
}

// ---------------- Stage 2: out[t] += w * (hmid @ W2[e] + b2[e]) ----------------
__launch_bounds__(256)
__global__ void gemm2_kernel(const unsigned short* __restrict__ hmid,
                             const float* __restrict__ W2,
                             const float* __restrict__ b2,
                             const int* __restrict__ cnt,
                             const int* __restrict__ base,
                             const int* __restrict__ list,
                             const float* __restrict__ tokw,
                             float* __restrict__ out) {
  const int e = blockIdx.z;
  const int c = cnt[e];
  const int m0 = blockIdx.y * 128;
  if (m0 >= c) return;
  const int n0 = blockIdx.x * 128;

  __shared__ int ents[128];
  __shared__ int arow[128];
  __shared__ __align__(16) unsigned short As[128 * 40];
  __shared__ __align__(16) unsigned short Bs[128 * 40];

  const int tid = threadIdx.x;
  const int hb = base[e];
  if (tid < 128) {
    int idx = m0 + tid; if (idx >= c) idx = c - 1;
    ents[tid] = list[e * CAP + idx];
    arow[tid] = hb + idx;
  }
  __syncthreads();

  const int lane = tid & 63;
  const int wave = tid >> 6;
  const int wm = (wave >> 1) * 64;
  const int wn = (wave & 1) * 64;
  const int l16 = lane & 15;
  const int quad = lane >> 4;

  f32x4 acc[16];
#pragma unroll
  for (int i = 0; i < 16; ++i) acc[i] = (f32x4){0.f, 0.f, 0.f, 0.f};

  const float* W2e = W2 + (size_t)e * I_DIM * H_DIM;

  for (int kt = 0; kt < I_DIM / 32; ++kt) {
    const int k0 = kt * 32;
    // A: 128 rows x 32 k bf16 (already bf16) -> LDS, 16B chunks
#pragma unroll
    for (int i = 0; i < 2; ++i) {
      const int idx = tid + i * 256;
      const int row = idx >> 2, kg = idx & 3;
      const f32x4 v = *(const f32x4*)(hmid + (size_t)arow[row] * I_DIM + k0 + kg * 8);
      *(f32x4*)&As[row * 40 + kg * 8] = v;
    }
    // B: [n][k] transposed stage, conflict-free b128 writes.
#pragma unroll
    for (int i = 0; i < 2; ++i) {
      const int idx = tid + i * 256;
      const int n = idx & 127, g = idx >> 7;
      const float* src = W2e + (size_t)(k0 + g * 8) * H_DIM + n0 + n;
      unsigned short tmp[8];
#pragma unroll
      for (int kk = 0; kk < 8; ++kk)
        tmp[kk] = f2bf(src[(size_t)kk * H_DIM]);
      *(f32x4*)&Bs[n * 40 + g * 8] = *(const f32x4*)tmp;
    }
    __syncthreads();
    bf16x8 a[4], b[4];
#pragma unroll
    for (int mf = 0; mf < 4; ++mf)
      a[mf] = *(const bf16x8*)&As[(wm + mf * 16 + l16) * 40 + quad * 8];
#pragma unroll
    for (int nf = 0; nf < 4; ++nf)
      b[nf] = *(const bf16x8*)&Bs[(wn + nf * 16 + l16) * 40 + quad * 8];
#pragma unroll
    for (int mf = 0; mf < 4; ++mf)
#pragma unroll
      for (int nf = 0; nf < 4; ++nf)
        acc[mf * 4 + nf] = __builtin_amdgcn_mfma_f32_16x16x32_bf16(
            a[mf], b[nf], acc[mf * 4 + nf], 0, 0, 0);
    __syncthreads();
  }

#pragma unroll
  for (int mf = 0; mf < 4; ++mf) {
#pragma unroll
    for (int reg = 0; reg < 4; ++reg) {
      const int row = wm + mf * 16 + quad * 4 + reg;
      const int gr = m0 + row;
      if (gr < c) {
        const int ent = ents[row];
        const int t = ent >> 1;
        const float wgt = tokw[ent];
#pragma unroll
        for (int nf = 0; nf < 4; ++nf) {
          const int col = n0 + wn + nf * 16 + l16;
          const float v = acc[mf * 4 + nf][reg] + b2[e * H_DIM + col];
          atomicAdd(&out[(size_t)t * H_DIM + col], wgt * v);
        }
      }
    }
  }
}

extern "C" void kernel_launch(void* const* d_in, const int* in_sizes, int n_in,
                              void* d_out, int out_size, void* d_ws, size_t ws_size,
                              hipStream_t stream) {
  (void)in_sizes; (void)n_in; (void)ws_size;
  const float* x  = (const float*)d_in[0];
  const float* gw = (const float*)d_in[1];
  const float* gb = (const float*)d_in[2];
  const float* W1 = (const float*)d_in[3];
  const float* b1 = (const float*)d_in[4];
  const float* W2 = (const float*)d_in[5];
  const float* b2 = (const float*)d_in[6];
  float* out = (float*)d_out;

  char* w = (char*)d_ws;
  int* cnt   = (int*)w;                                   // 32 B
  int* base  = (int*)(w + 32);                            // 32 B
  int* list  = (int*)(w + 256);                           // 8*8192*4 = 256 KB
  float* tokw = (float*)(w + 256 + CAP * E_NUM * 4);      // 32 KB
  unsigned short* hmid = (unsigned short*)(w + 295168);   // 8192*4096*2 = 64 MB

  hipMemsetAsync(cnt, 0, 32, stream);
  hipMemsetAsync(out, 0, (size_t)out_size * sizeof(float), stream);

  router_kernel<<<T_NUM, 64, 0, stream>>>(x, gw, gb, cnt, list, tokw);
  scan_kernel<<<1, 64, 0, stream>>>(cnt, base);
  gemm1_kernel<<<dim3(I_DIM / 128, CAP / 128, E_NUM), 256, 0, stream>>>(
      x, W1, b1, cnt, base, list, hmid);
  gemm2_kernel<<<dim3(H_DIM / 128, CAP / 128, E_NUM), 256, 0, stream>>>(
      hmid, W2, b2, cnt, base, list, tokw, out);
}

// Round 3
// 690.977 us; speedup vs baseline: 1.6688x; 1.0868x over previous
//
#include <hip/hip_runtime.h>
#include <hip/hip_bf16.h>
#include <math.h>

// Problem constants (H=1024, E=8, I=4096, T=B*S=4096)
#define H_DIM 1024
#define E_NUM 8
#define I_DIM 4096
#define T_NUM 4096
#define CAP   8192   // 2*T worst-case pairs per expert

typedef __attribute__((ext_vector_type(8))) short bf16x8;
typedef __attribute__((ext_vector_type(4))) float f32x4;

typedef const __attribute__((address_space(1))) void* gptr_t;
typedef __attribute__((address_space(3))) void* lptr_t;

__device__ inline unsigned short f2bf(float f) {
  union { __hip_bfloat16 h; unsigned short u; } cv;
  cv.h = __float2bfloat16(f);   // RNE
  return cv.u;
}

// ---------------- Router: 1 wave per token ----------------
__global__ void router_kernel(const float* __restrict__ x,
                              const float* __restrict__ gw,
                              const float* __restrict__ gb,
                              int* __restrict__ cnt,
                              int* __restrict__ list,
                              float* __restrict__ tokw) {
  const int t = blockIdx.x;
  const int l = threadIdx.x;
  const float* xr = x + (size_t)t * H_DIM;
  float acc[E_NUM];
#pragma unroll
  for (int e = 0; e < E_NUM; ++e) acc[e] = 0.f;
#pragma unroll
  for (int j = 0; j < H_DIM / 64; ++j) {
    const int h = l + j * 64;
    const float xv = xr[h];
    const float4* g = (const float4*)(gw + (size_t)h * E_NUM);
    const float4 g0 = g[0], g1 = g[1];
    acc[0] += xv * g0.x; acc[1] += xv * g0.y; acc[2] += xv * g0.z; acc[3] += xv * g0.w;
    acc[4] += xv * g1.x; acc[5] += xv * g1.y; acc[6] += xv * g1.z; acc[7] += xv * g1.w;
  }
#pragma unroll
  for (int off = 32; off > 0; off >>= 1) {
#pragma unroll
    for (int e = 0; e < E_NUM; ++e) acc[e] += __shfl_down(acc[e], off, 64);
  }
  if (l == 0) {
    float lg[E_NUM], mx = -1e30f;
#pragma unroll
    for (int e = 0; e < E_NUM; ++e) { lg[e] = acc[e] + gb[e]; mx = fmaxf(mx, lg[e]); }
    float p[E_NUM], s = 0.f;
#pragma unroll
    for (int e = 0; e < E_NUM; ++e) { p[e] = expf(lg[e] - mx); s += p[e]; }
    const float inv = 1.f / s;
#pragma unroll
    for (int e = 0; e < E_NUM; ++e) p[e] *= inv;
    int i0 = 0;
#pragma unroll
    for (int e = 1; e < E_NUM; ++e) if (p[e] > p[i0]) i0 = e;
    int i1 = (i0 == 0) ? 1 : 0;
#pragma unroll
    for (int e = 0; e < E_NUM; ++e) if (e != i0 && p[e] > p[i1]) i1 = e;
    const float denom = p[i0] + p[i1] + 1e-6f;
    const float w0 = p[i0] / denom, w1 = p[i1] / denom;
    int pos = atomicAdd(&cnt[i0], 1);
    list[i0 * CAP + pos] = t * 2;
    tokw[t * 2] = w0;
    pos = atomicAdd(&cnt[i1], 1);
    list[i1 * CAP + pos] = t * 2 + 1;
    tokw[t * 2 + 1] = w1;
  }
}

// ---------------- Scan ----------------
__global__ void scan_kernel(const int* __restrict__ cnt, int* __restrict__ base) {
  if (threadIdx.x == 0 && blockIdx.x == 0) {
    int b = 0;
    for (int e = 0; e < E_NUM; ++e) { base[e] = b; b += cnt[e]; }
  }
}

// ---------------- x -> bf16 ----------------
__launch_bounds__(256)
__global__ void cvt_x_kernel(const float* __restrict__ x, unsigned short* __restrict__ xb) {
  const size_t i = ((size_t)blockIdx.x * 256 + threadIdx.x) * 8;
  const float4 v0 = *(const float4*)(x + i);
  const float4 v1 = *(const float4*)(x + i + 4);
  unsigned short t[8];
  t[0] = f2bf(v0.x); t[1] = f2bf(v0.y); t[2] = f2bf(v0.z); t[3] = f2bf(v0.w);
  t[4] = f2bf(v1.x); t[5] = f2bf(v1.y); t[6] = f2bf(v1.z); t[7] = f2bf(v1.w);
  *(f32x4*)(xb + i) = *(const f32x4*)t;
}

// ---------------- per-expert fp32 [R][C] -> bf16 [C][R] (k-contiguous) ----------------
// Tile 32 R x 128 C per block. LDS [r][c] ld=130 u16 (write 2-way/free, read conflict-free).
__launch_bounds__(256)
__global__ void transpose_cvt_kernel(const float* __restrict__ src,
                                     unsigned short* __restrict__ dst,
                                     int R, int C) {
  const int e = blockIdx.z;
  const int r0 = blockIdx.y * 32;
  const int c0 = blockIdx.x * 128;
  const float* s = src + (size_t)e * R * C;
  unsigned short* d = dst + (size_t)e * R * C;
  __shared__ unsigned short Lt[32 * 130];
  const int tid = threadIdx.x;
#pragma unroll
  for (int m = 0; m < 4; ++m) {
    const int li = tid + m * 256;          // 0..1023
    const int r = li >> 5;                 // 0..31
    const int cg = (li & 31) * 4;          // 0..124
    const float4 v = *(const float4*)(s + (size_t)(r0 + r) * C + c0 + cg);
    Lt[r * 130 + cg + 0] = f2bf(v.x);
    Lt[r * 130 + cg + 1] = f2bf(v.y);
    Lt[r * 130 + cg + 2] = f2bf(v.z);
    Lt[r * 130 + cg + 3] = f2bf(v.w);
  }
  __syncthreads();
#pragma unroll
  for (int m = 0; m < 2; ++m) {
    const int li = tid + m * 256;          // 0..511
    const int col = li >> 2;               // 0..127
    const int rg = (li & 3) * 8;           // 0,8,16,24
    unsigned short tmp[8];
#pragma unroll
    for (int j = 0; j < 8; ++j) tmp[j] = Lt[(rg + j) * 130 + col];
    *(f32x4*)(d + (size_t)(c0 + col) * R + r0 + rg) = *(const f32x4*)tmp;
  }
}

// ---------------- Stage 1 (preconverted): hmid = gelu(xb @ W1t^T + b1) ----------------
// 128x128 tile, BK=32, all-bf16, global_load_lds staging, unpadded LDS ld=32.
__launch_bounds__(256)
__global__ void gemm1_pre_kernel(const unsigned short* __restrict__ xb,
                                 const unsigned short* __restrict__ W1t,
                                 const float* __restrict__ b1,
                                 const int* __restrict__ cnt,
                                 const int* __restrict__ base,
                                 const int* __restrict__ list,
                                 unsigned short* __restrict__ hmid) {
  const int e = blockIdx.z;
  const int c = cnt[e];
  const int m0 = blockIdx.y * 128;
  if (m0 >= c) return;
  const int n0 = blockIdx.x * 128;

  __shared__ int toks[128];
  __shared__ __align__(16) unsigned short As[128 * 32];
  __shared__ __align__(16) unsigned short Bs[128 * 32];

  const int tid = threadIdx.x;
  if (tid < 128) {
    int idx = m0 + tid; if (idx >= c) idx = c - 1;
    toks[tid] = list[e * CAP + idx] >> 1;
  }
  __syncthreads();

  const int lane = tid & 63;
  const int wave = tid >> 6;
  const int wm = (wave >> 1) * 64;
  const int wn = (wave & 1) * 64;
  const int l16 = lane & 15;
  const int quad = lane >> 4;

  // chunk c = tid (round 0) / tid+256 (round 1); row=c>>2, k-elem=(c&3)*8
  const int rA0 = tid >> 2;
  const int rA1 = rA0 + 64;
  const int kg0 = (tid & 3) * 8;
  const unsigned short* W1e = W1t + (size_t)e * H_DIM * I_DIM;  // [I][H]

  const unsigned short* aSrc0 = xb + (size_t)toks[rA0] * H_DIM + kg0;
  const unsigned short* aSrc1 = xb + (size_t)toks[rA1] * H_DIM + kg0;
  const unsigned short* bSrc0 = W1e + (size_t)(n0 + rA0) * H_DIM + kg0;
  const unsigned short* bSrc1 = W1e + (size_t)(n0 + rA1) * H_DIM + kg0;
  char* aDst0 = (char*)As + wave * 1024;
  char* aDst1 = (char*)As + 4096 + wave * 1024;
  char* bDst0 = (char*)Bs + wave * 1024;
  char* bDst1 = (char*)Bs + 4096 + wave * 1024;

  f32x4 acc[16];
#pragma unroll
  for (int i = 0; i < 16; ++i) acc[i] = (f32x4){0.f, 0.f, 0.f, 0.f};

  for (int k0 = 0; k0 < H_DIM; k0 += 32) {
    __builtin_amdgcn_global_load_lds((gptr_t)(aSrc0 + k0), (lptr_t)aDst0, 16, 0, 0);
    __builtin_amdgcn_global_load_lds((gptr_t)(aSrc1 + k0), (lptr_t)aDst1, 16, 0, 0);
    __builtin_amdgcn_global_load_lds((gptr_t)(bSrc0 + k0), (lptr_t)bDst0, 16, 0, 0);
    __builtin_amdgcn_global_load_lds((gptr_t)(bSrc1 + k0), (lptr_t)bDst1, 16, 0, 0);
    __syncthreads();
    bf16x8 a[4], b[4];
#pragma unroll
    for (int mf = 0; mf < 4; ++mf)
      a[mf] = *(const bf16x8*)&As[(wm + mf * 16 + l16) * 32 + quad * 8];
#pragma unroll
    for (int nf = 0; nf < 4; ++nf)
      b[nf] = *(const bf16x8*)&Bs[(wn + nf * 16 + l16) * 32 + quad * 8];
#pragma unroll
    for (int mf = 0; mf < 4; ++mf)
#pragma unroll
      for (int nf = 0; nf < 4; ++nf)
        acc[mf * 4 + nf] = __builtin_amdgcn_mfma_f32_16x16x32_bf16(
            a[mf], b[nf], acc[mf * 4 + nf], 0, 0, 0);
    __syncthreads();
  }

  const int hb = base[e];
#pragma unroll
  for (int mf = 0; mf < 4; ++mf) {
#pragma unroll
    for (int reg = 0; reg < 4; ++reg) {
      const int row = wm + mf * 16 + quad * 4 + reg;
      const int gr = m0 + row;
      if (gr < c) {
#pragma unroll
        for (int nf = 0; nf < 4; ++nf) {
          const int col = n0 + wn + nf * 16 + l16;
          const float v = acc[mf * 4 + nf][reg] + b1[e * I_DIM + col];
          const float u = v + 0.044715f * v * v * v;
          // gelu_tanh(v) = v / (1 + e^{-2*0.79788456*u})
          const float g = v / (1.f + __expf(-1.5957691216057308f * u));
          hmid[(size_t)(hb + gr) * I_DIM + col] = f2bf(g);
        }
      }
    }
  }
}

// ---------------- Stage 2 (preconverted): out += w * (hmid @ W2t^T + b2) ----------------
__launch_bounds__(256)
__global__ void gemm2_pre_kernel(const unsigned short* __restrict__ hmid,
                                 const unsigned short* __restrict__ W2t,
                                 const float* __restrict__ b2,
                                 const int* __restrict__ cnt,
                                 const int* __restrict__ base,
                                 const int* __restrict__ list,
                                 const float* __restrict__ tokw,
                                 float* __restrict__ out) {
  const int e = blockIdx.z;
  const int c = cnt[e];
  const int m0 = blockIdx.y * 128;
  if (m0 >= c) return;
  const int n0 = blockIdx.x * 128;

  __shared__ int ents[128];
  __shared__ int arow[128];
  __shared__ __align__(16) unsigned short As[128 * 32];
  __shared__ __align__(16) unsigned short Bs[128 * 32];

  const int tid = threadIdx.x;
  const int hb = base[e];
  if (tid < 128) {
    int idx = m0 + tid; if (idx >= c) idx = c - 1;
    ents[tid] = list[e * CAP + idx];
    arow[tid] = hb + idx;
  }
  __syncthreads();

  const int lane = tid & 63;
  const int wave = tid >> 6;
  const int wm = (wave >> 1) * 64;
  const int wn = (wave & 1) * 64;
  const int l16 = lane & 15;
  const int quad = lane >> 4;

  const int rA0 = tid >> 2;
  const int rA1 = rA0 + 64;
  const int kg0 = (tid & 3) * 8;
  const unsigned short* W2e = W2t + (size_t)e * I_DIM * H_DIM;  // [H][I]

  const unsigned short* aSrc0 = hmid + (size_t)arow[rA0] * I_DIM + kg0;
  const unsigned short* aSrc1 = hmid + (size_t)arow[rA1] * I_DIM + kg0;
  const unsigned short* bSrc0 = W2e + (size_t)(n0 + rA0) * I_DIM + kg0;
  const unsigned short* bSrc1 = W2e + (size_t)(n0 + rA1) * I_DIM + kg0;
  char* aDst0 = (char*)As + wave * 1024;
  char* aDst1 = (char*)As + 4096 + wave * 1024;
  char* bDst0 = (char*)Bs + wave * 1024;
  char* bDst1 = (char*)Bs + 4096 + wave * 1024;

  f32x4 acc[16];
#pragma unroll
  for (int i = 0; i < 16; ++i) acc[i] = (f32x4){0.f, 0.f, 0.f, 0.f};

  for (int k0 = 0; k0 < I_DIM; k0 += 32) {
    __builtin_amdgcn_global_load_lds((gptr_t)(aSrc0 + k0), (lptr_t)aDst0, 16, 0, 0);
    __builtin_amdgcn_global_load_lds((gptr_t)(aSrc1 + k0), (lptr_t)aDst1, 16, 0, 0);
    __builtin_amdgcn_global_load_lds((gptr_t)(bSrc0 + k0), (lptr_t)bDst0, 16, 0, 0);
    __builtin_amdgcn_global_load_lds((gptr_t)(bSrc1 + k0), (lptr_t)bDst1, 16, 0, 0);
    __syncthreads();
    bf16x8 a[4], b[4];
#pragma unroll
    for (int mf = 0; mf < 4; ++mf)
      a[mf] = *(const bf16x8*)&As[(wm + mf * 16 + l16) * 32 + quad * 8];
#pragma unroll
    for (int nf = 0; nf < 4; ++nf)
      b[nf] = *(const bf16x8*)&Bs[(wn + nf * 16 + l16) * 32 + quad * 8];
#pragma unroll
    for (int mf = 0; mf < 4; ++mf)
#pragma unroll
      for (int nf = 0; nf < 4; ++nf)
        acc[mf * 4 + nf] = __builtin_amdgcn_mfma_f32_16x16x32_bf16(
            a[mf], b[nf], acc[mf * 4 + nf], 0, 0, 0);
    __syncthreads();
  }

#pragma unroll
  for (int mf = 0; mf < 4; ++mf) {
#pragma unroll
    for (int reg = 0; reg < 4; ++reg) {
      const int row = wm + mf * 16 + quad * 4 + reg;
      const int gr = m0 + row;
      if (gr < c) {
        const int ent = ents[row];
        const int t = ent >> 1;
        const float wgt = tokw[ent];
#pragma unroll
        for (int nf = 0; nf < 4; ++nf) {
          const int col = n0 + wn + nf * 16 + l16;
          const float v = acc[mf * 4 + nf][reg] + b2[e * H_DIM + col];
          atomicAdd(&out[(size_t)t * H_DIM + col], wgt * v);
        }
      }
    }
  }
}

// ================= Fallback path (round-2 kernels, used if ws too small) =================
__launch_bounds__(256)
__global__ void gemm1_fb_kernel(const float* __restrict__ x,
                                const float* __restrict__ W1,
                                const float* __restrict__ b1,
                                const int* __restrict__ cnt,
                                const int* __restrict__ base,
                                const int* __restrict__ list,
                                unsigned short* __restrict__ hmid) {
  const int e = blockIdx.z;
  const int c = cnt[e];
  const int m0 = blockIdx.y * 128;
  if (m0 >= c) return;
  const int n0 = blockIdx.x * 128;
  __shared__ int toks[128];
  __shared__ __align__(16) unsigned short As[128 * 40];
  __shared__ __align__(16) unsigned short Bs[128 * 40];
  const int tid = threadIdx.x;
  if (tid < 128) {
    int idx = m0 + tid; if (idx >= c) idx = c - 1;
    toks[tid] = list[e * CAP + idx] >> 1;
  }
  __syncthreads();
  const int lane = tid & 63, wave = tid >> 6;
  const int wm = (wave >> 1) * 64, wn = (wave & 1) * 64;
  const int l16 = lane & 15, quad = lane >> 4;
  f32x4 acc[16];
#pragma unroll
  for (int i = 0; i < 16; ++i) acc[i] = (f32x4){0.f, 0.f, 0.f, 0.f};
  const float* W1e = W1 + (size_t)e * H_DIM * I_DIM;
  for (int kt = 0; kt < H_DIM / 32; ++kt) {
    const int k0 = kt * 32;
#pragma unroll
    for (int i = 0; i < 2; ++i) {
      const int idx = tid + i * 256;
      const int row = idx >> 2, g = idx & 3;
      const float* src = x + (size_t)toks[row] * H_DIM + k0 + g * 8;
      const float4 v0 = *(const float4*)(src);
      const float4 v1 = *(const float4*)(src + 4);
      unsigned short tmp[8];
      tmp[0] = f2bf(v0.x); tmp[1] = f2bf(v0.y); tmp[2] = f2bf(v0.z); tmp[3] = f2bf(v0.w);
      tmp[4] = f2bf(v1.x); tmp[5] = f2bf(v1.y); tmp[6] = f2bf(v1.z); tmp[7] = f2bf(v1.w);
      *(f32x4*)&As[row * 40 + g * 8] = *(const f32x4*)tmp;
    }
#pragma unroll
    for (int i = 0; i < 2; ++i) {
      const int idx = tid + i * 256;
      const int n = idx & 127, g = idx >> 7;
      const float* src = W1e + (size_t)(k0 + g * 8) * I_DIM + n0 + n;
      unsigned short tmp[8];
#pragma unroll
      for (int kk = 0; kk < 8; ++kk) tmp[kk] = f2bf(src[(size_t)kk * I_DIM]);
      *(f32x4*)&Bs[n * 40 + g * 8] = *(const f32x4*)tmp;
    }
    __syncthreads();
    bf16x8 a[4], b[4];
#pragma unroll
    for (int mf = 0; mf < 4; ++mf)
      a[mf] = *(const bf16x8*)&As[(wm + mf * 16 + l16) * 40 + quad * 8];
#pragma unroll
    for (int nf = 0; nf < 4; ++nf)
      b[nf] = *(const bf16x8*)&Bs[(wn + nf * 16 + l16) * 40 + quad * 8];
#pragma unroll
    for (int mf = 0; mf < 4; ++mf)
#pragma unroll
      for (int nf = 0; nf < 4; ++nf)
        acc[mf * 4 + nf] = __builtin_amdgcn_mfma_f32_16x16x32_bf16(
            a[mf], b[nf], acc[mf * 4 + nf], 0, 0, 0);
    __syncthreads();
  }
  const int hb = base[e];
#pragma unroll
  for (int mf = 0; mf < 4; ++mf)
#pragma unroll
    for (int reg = 0; reg < 4; ++reg) {
      const int row = wm + mf * 16 + quad * 4 + reg;
      const int gr = m0 + row;
      if (gr < c) {
#pragma unroll
        for (int nf = 0; nf < 4; ++nf) {
          const int col = n0 + wn + nf * 16 + l16;
          const float v = acc[mf * 4 + nf][reg] + b1[e * I_DIM + col];
          const float u = v + 0.044715f * v * v * v;
          const float g = v / (1.f + __expf(-1.5957691216057308f * u));
          hmid[(size_t)(hb + gr) * I_DIM + col] = f2bf(g);
        }
      }
    }
}

__launch_bounds__(256)
__global__ void gemm2_fb_kernel(const unsigned short* __restrict__ hmid,
                                const float* __restrict__ W2,
                                const float* __restrict__ b2,
                                const int* __restrict__ cnt,
                                const int* __restrict__ base,
                                const int* __restrict__ list,
                                const float* __restrict__ tokw,
                                float* __restrict__ out) {
  const int e = blockIdx.z;
  const int c = cnt[e];
  const int m0 = blockIdx.y * 128;
  if (m0 >= c) return;
  const int n0 = blockIdx.x * 128;
  __shared__ int ents[128];
  __shared__ int arow[128];
  __shared__ __align__(16) unsigned short As[128 * 40];
  __shared__ __align__(16) unsigned short Bs[128 * 40];
  const int tid = threadIdx.x;
  const int hb = base[e];
  if (tid < 128) {
    int idx = m0 + tid; if (idx >= c) idx = c - 1;
    ents[tid] = list[e * CAP + idx];
    arow[tid] = hb + idx;
  }
  __syncthreads();
  const int lane = tid & 63, wave = tid >> 6;
  const int wm = (wave >> 1) * 64, wn = (wave & 1) * 64;
  const int l16 = lane & 15, quad = lane >> 4;
  f32x4 acc[16];
#pragma unroll
  for (int i = 0; i < 16; ++i) acc[i] = (f32x4){0.f, 0.f, 0.f, 0.f};
  const float* W2e = W2 + (size_t)e * I_DIM * H_DIM;
  for (int kt = 0; kt < I_DIM / 32; ++kt) {
    const int k0 = kt * 32;
#pragma unroll
    for (int i = 0; i < 2; ++i) {
      const int idx = tid + i * 256;
      const int row = idx >> 2, kg = idx & 3;
      const f32x4 v = *(const f32x4*)(hmid + (size_t)arow[row] * I_DIM + k0 + kg * 8);
      *(f32x4*)&As[row * 40 + kg * 8] = v;
    }
#pragma unroll
    for (int i = 0; i < 2; ++i) {
      const int idx = tid + i * 256;
      const int n = idx & 127, g = idx >> 7;
      const float* src = W2e + (size_t)(k0 + g * 8) * H_DIM + n0 + n;
      unsigned short tmp[8];
#pragma unroll
      for (int kk = 0; kk < 8; ++kk) tmp[kk] = f2bf(src[(size_t)kk * H_DIM]);
      *(f32x4*)&Bs[n * 40 + g * 8] = *(const f32x4*)tmp;
    }
    __syncthreads();
    bf16x8 a[4], b[4];
#pragma unroll
    for (int mf = 0; mf < 4; ++mf)
      a[mf] = *(const bf16x8*)&As[(wm + mf * 16 + l16) * 40 + quad * 8];
#pragma unroll
    for (int nf = 0; nf < 4; ++nf)
      b[nf] = *(const bf16x8*)&Bs[(wn + nf * 16 + l16) * 40 + quad * 8];
#pragma unroll
    for (int mf = 0; mf < 4; ++mf)
#pragma unroll
      for (int nf = 0; nf < 4; ++nf)
        acc[mf * 4 + nf] = __builtin_amdgcn_mfma_f32_16x16x32_bf16(
            a[mf], b[nf], acc[mf * 4 + nf], 0, 0, 0);
    __syncthreads();
  }
#pragma unroll
  for (int mf = 0; mf < 4; ++mf)
#pragma unroll
    for (int reg = 0; reg < 4; ++reg) {
      const int row = wm + mf * 16 + quad * 4 + reg;
      const int gr = m0 + row;
      if (gr < c) {
        const int ent = ents[row];
        const int t = ent >> 1;
        const float wgt = tokw[ent];
#pragma unroll
        for (int nf = 0; nf < 4; ++nf) {
          const int col = n0 + wn + nf * 16 + l16;
          const float v = acc[mf * 4 + nf][reg] + b2[e * H_DIM + col];
          atomicAdd(&out[(size_t)t * H_DIM + col], wgt * v);
        }
      }
    }
}

extern "C" void kernel_launch(void* const* d_in, const int* in_sizes, int n_in,
                              void* d_out, int out_size, void* d_ws, size_t ws_size,
                              hipStream_t stream) {
  (void)in_sizes; (void)n_in;
  const float* x  = (const float*)d_in[0];
  const float* gw = (const float*)d_in[1];
  const float* gb = (const float*)d_in[2];
  const float* W1 = (const float*)d_in[3];
  const float* b1 = (const float*)d_in[4];
  const float* W2 = (const float*)d_in[5];
  const float* b2 = (const float*)d_in[6];
  float* out = (float*)d_out;

  char* w = (char*)d_ws;
  int* cnt    = (int*)w;                                   // 32 B @ 0
  int* base   = (int*)(w + 32);                            // 32 B
  int* list   = (int*)(w + 256);                           // 256 KB -> 262400
  float* tokw = (float*)(w + 262400);                      // 32 KB  -> 295168
  unsigned short* hmid = (unsigned short*)(w + 295168);    // 64 MB  -> 67404032
  unsigned short* W1t  = (unsigned short*)(w + 67404032);  // 64 MB  -> 134512896
  unsigned short* W2t  = (unsigned short*)(w + 134512896); // 64 MB  -> 201621760
  unsigned short* xb   = (unsigned short*)(w + 201621760); // 8 MB   -> 210010368
  const size_t NEED = 210010368;

  hipMemsetAsync(cnt, 0, 32, stream);
  hipMemsetAsync(out, 0, (size_t)out_size * sizeof(float), stream);

  router_kernel<<<T_NUM, 64, 0, stream>>>(x, gw, gb, cnt, list, tokw);
  scan_kernel<<<1, 64, 0, stream>>>(cnt, base);

  if (ws_size >= NEED) {
    cvt_x_kernel<<<T_NUM * H_DIM / 2048, 256, 0, stream>>>(x, xb);
    transpose_cvt_kernel<<<dim3(I_DIM / 128, H_DIM / 32, E_NUM), 256, 0, stream>>>(
        W1, W1t, H_DIM, I_DIM);
    transpose_cvt_kernel<<<dim3(H_DIM / 128, I_DIM / 32, E_NUM), 256, 0, stream>>>(
        W2, W2t, I_DIM, H_DIM);
    gemm1_pre_kernel<<<dim3(I_DIM / 128, CAP / 128, E_NUM), 256, 0, stream>>>(
        xb, W1t, b1, cnt, base, list, hmid);
    gemm2_pre_kernel<<<dim3(H_DIM / 128, CAP / 128, E_NUM), 256, 0, stream>>>(
        hmid, W2t, b2, cnt, base, list, tokw, out);
  } else {
    gemm1_fb_kernel<<<dim3(I_DIM / 128, CAP / 128, E_NUM), 256, 0, stream>>>(
        x, W1, b1, cnt, base, list, hmid);
    gemm2_fb_kernel<<<dim3(H_DIM / 128, CAP / 128, E_NUM), 256, 0, stream>>>(
        hmid, W2, b2, cnt, base, list, tokw, out);
  }
}